// Round 6
// baseline (12471.356 us; speedup 1.0000x reference)
//
#include <hip/hip_runtime.h>
#include <math.h>

// Problem constants
#define Bb 8
#define Nn 4096
#define DIMv 512
#define Hh 8
#define Dd 64
#define Mm 256
#define Ll 16
#define BH 64           // Bb*Hh
#define QKV_N 1536
#define QKV_K 512

#define NQD 16777216u   // BH*Nn*Dd
#define MDsz 1048576u   // BH*Mm*Dd
#define MMsz 4194304u   // BH*Mm*Mm

#define DEV __device__ __forceinline__

DEV float wave_max(float v) {
  #pragma unroll
  for (int m = 32; m >= 1; m >>= 1) v = fmaxf(v, __shfl_xor(v, m, 64));
  return v;
}
DEV float wave_sum(float v) {
  #pragma unroll
  for (int m = 32; m >= 1; m >>= 1) v += __shfl_xor(v, m, 64);
  return v;
}

// ---------------- qkv GEMM: [32768x512]@[512x1536] scattered to q/k/v [b,h,n,d] ----------------
__global__ __launch_bounds__(256) void k_qkv(const float* __restrict__ x,
                                             const float* __restrict__ w,
                                             float* __restrict__ q,
                                             float* __restrict__ kk_,
                                             float* __restrict__ v) {
  __shared__ float As[16][68];
  __shared__ float Bs[16][68];
  const int row0 = blockIdx.x * 64;
  const int col0 = blockIdx.y * 64;
  const int tid = threadIdx.x;
  const int tx = tid & 15, ty = tid >> 4;
  float acc[4][4];
  #pragma unroll
  for (int i = 0; i < 4; ++i)
    #pragma unroll
    for (int j = 0; j < 4; ++j) acc[i][j] = 0.f;

  const int ac = tid & 15, ar0 = tid >> 4;
  const int bc = tid & 63, br0 = tid >> 6;
  for (int kt = 0; kt < QKV_K; kt += 16) {
    #pragma unroll
    for (int u = 0; u < 4; ++u) {
      int ar = ar0 + u * 16;
      As[ac][ar] = x[(size_t)(row0 + ar) * QKV_K + kt + ac];
      int br = br0 + u * 4;
      Bs[br][bc] = w[(size_t)(kt + br) * QKV_N + col0 + bc];
    }
    __syncthreads();
    #pragma unroll
    for (int kq = 0; kq < 16; ++kq) {
      float4 a4 = *(const float4*)&As[kq][ty * 4];
      float4 b4 = *(const float4*)&Bs[kq][tx * 4];
      float av[4] = {a4.x, a4.y, a4.z, a4.w};
      float bv[4] = {b4.x, b4.y, b4.z, b4.w};
      #pragma unroll
      for (int i = 0; i < 4; ++i)
        #pragma unroll
        for (int j = 0; j < 4; ++j) acc[i][j] += av[i] * bv[j];
    }
    __syncthreads();
  }
  // scatter: col block is 64-aligned -> single dest tensor & head per block
  const int which = col0 >> 9;
  const int hh = (col0 & 511) >> 6;
  float* dst = which == 0 ? q : (which == 1 ? kk_ : v);
  const float sc = (which == 0) ? 0.125f : 1.0f;  // q * d^-0.5
  #pragma unroll
  for (int i = 0; i < 4; ++i) {
    int r = row0 + ty * 4 + i;
    int bb = r >> 12, ii = r & 4095;
    float* o = dst + (((size_t)(bb * Hh + hh) * Nn) + ii) * Dd + tx * 4;
    #pragma unroll
    for (int j = 0; j < 4; ++j) o[j] = acc[i][j] * sc;
  }
}

// ---------------- landmark means ----------------
__global__ __launch_bounds__(256) void k_lmeans(const float* __restrict__ q, const float* __restrict__ k,
                                                float* __restrict__ ql, float* __restrict__ kl) {
  int idx = blockIdx.x * 256 + threadIdx.x;   // [0, BH*M*D)
  int dd = idx & 63;
  int mi = (idx >> 6) & 255;
  int bh = idx >> 14;
  const float* qp = q + ((size_t)bh * Nn + mi * Ll) * Dd + dd;
  const float* kp = k + ((size_t)bh * Nn + mi * Ll) * Dd + dd;
  float sq = 0.f, sk = 0.f;
  #pragma unroll
  for (int l = 0; l < Ll; ++l) { sq += qp[(size_t)l * Dd]; sk += kp[(size_t)l * Dd]; }
  ql[idx] = sq * (1.f / 16.f);
  kl[idx] = sk * (1.f / 16.f);
}

// ---------------- fused: z3 = softmax(ql @ k^T, axis=n) @ v  (one wave per landmark row) ----------------
__global__ __launch_bounds__(256) void k_attn3v(const float* __restrict__ ql, const float* __restrict__ k,
                                                const float* __restrict__ v, float* __restrict__ z3) {
  int wid = (blockIdx.x * 256 + threadIdx.x) >> 6;  // [0, BH*M)
  int lane = threadIdx.x & 63;
  int bh = wid >> 8, i = wid & 255;
  const float* qr = ql + ((size_t)bh * Mm + i) * Dd;
  float4 qrow[16];
  #pragma unroll
  for (int t = 0; t < 16; ++t) qrow[t] = ((const float4*)qr)[t];
  const float* kb = k + (size_t)bh * Nn * Dd;
  const float* vb = v + (size_t)bh * Nn * Dd;
  float m = -1e30f, s = 0.f, acc = 0.f;
  for (int t = 0; t < 64; ++t) {
    const float* krow = kb + (size_t)(t * 64 + lane) * Dd;
    float logit = 0.f;
    #pragma unroll
    for (int u = 0; u < 16; ++u) {
      float4 kv4 = ((const float4*)krow)[u];
      logit += qrow[u].x * kv4.x + qrow[u].y * kv4.y + qrow[u].z * kv4.z + qrow[u].w * kv4.w;
    }
    float tmax = wave_max(logit);
    float nm = fmaxf(m, tmax);
    float corr = __expf(m - nm);
    float p = __expf(logit - nm);
    s = s * corr + wave_sum(p);
    acc *= corr;
    m = nm;
    const float* vrow = vb + (size_t)(t * 64) * Dd + lane;
    #pragma unroll 16
    for (int j = 0; j < 64; ++j) {
      float pj = __shfl(p, j, 64);
      acc += pj * vrow[(size_t)j * Dd];
    }
  }
  z3[((size_t)bh * Mm + i) * Dd + lane] = acc / s;
}

// ---------------- sim2 = ql @ kl^T (batched NT, K=64) ----------------
__global__ __launch_bounds__(256) void k_sim2(const float* __restrict__ ql, const float* __restrict__ kl,
                                              float* __restrict__ X) {
  __shared__ float As[16][68];
  __shared__ float Bs[16][68];
  int bh = blockIdx.z;
  const float* A = ql + (size_t)bh * Mm * Dd;
  const float* Bm = kl + (size_t)bh * Mm * Dd;
  float* C = X + (size_t)bh * Mm * Mm;
  int row0 = blockIdx.y * 64, col0 = blockIdx.x * 64;
  int tid = threadIdx.x, tx = tid & 15, ty = tid >> 4;
  float acc[4][4];
  #pragma unroll
  for (int i = 0; i < 4; ++i)
    #pragma unroll
    for (int j = 0; j < 4; ++j) acc[i][j] = 0.f;
  const int ac = tid & 15, ar0 = tid >> 4;
  for (int kt = 0; kt < Dd; kt += 16) {
    #pragma unroll
    for (int u = 0; u < 4; ++u) {
      int ar = ar0 + u * 16;
      As[ac][ar] = A[(size_t)(row0 + ar) * Dd + kt + ac];
      Bs[ac][ar] = Bm[(size_t)(col0 + ar) * Dd + kt + ac];
    }
    __syncthreads();
    #pragma unroll
    for (int kq = 0; kq < 16; ++kq) {
      float4 a4 = *(const float4*)&As[kq][ty * 4];
      float4 b4 = *(const float4*)&Bs[kq][tx * 4];
      float av[4] = {a4.x, a4.y, a4.z, a4.w};
      float bv[4] = {b4.x, b4.y, b4.z, b4.w};
      #pragma unroll
      for (int i = 0; i < 4; ++i)
        #pragma unroll
        for (int j = 0; j < 4; ++j) acc[i][j] += av[i] * bv[j];
    }
    __syncthreads();
  }
  #pragma unroll
  for (int i = 0; i < 4; ++i)
    #pragma unroll
    for (int j = 0; j < 4; ++j)
      C[(size_t)(row0 + ty * 4 + i) * Mm + col0 + tx * 4 + j] = acc[i][j];
}

// ---------------- row softmax of X (rows of 256); rowsum -> rs_part[row] ----------------
__global__ __launch_bounds__(64) void k_softmax2(float* __restrict__ X, float* __restrict__ rs_part) {
  int row = blockIdx.x;           // [0, BH*M)
  float* p = X + (size_t)row * Mm;
  int lane = threadIdx.x;
  float vals[4];
  float mx = -1e30f;
  #pragma unroll
  for (int t = 0; t < 4; ++t) { vals[t] = p[lane + 64 * t]; mx = fmaxf(mx, vals[t]); }
  mx = wave_max(mx);
  float s = 0.f;
  #pragma unroll
  for (int t = 0; t < 4; ++t) { vals[t] = __expf(vals[t] - mx); s += vals[t]; }
  s = wave_sum(s);
  float inv = 1.f / s;
  float rs = 0.f;
  #pragma unroll
  for (int t = 0; t < 4; ++t) { float o = vals[t] * inv; p[lane + 64 * t] = o; rs += o; }
  rs = wave_sum(rs);
  if (lane == 0) rs_part[row] = rs;
}

// ---------------- column sums of attn2 -> cs_part[bh*256+j] ----------------
__global__ __launch_bounds__(256) void k_colsum(const float* __restrict__ X, float* __restrict__ cs_part) {
  int bh = blockIdx.x, j = threadIdx.x;
  const float* p = X + (size_t)bh * Mm * Mm + j;
  float s = 0.f;
  for (int i = 0; i < Mm; ++i) s += p[(size_t)i * Mm];
  cs_part[bh * Mm + j] = s;
}

// ---------------- global maxes of rs_part / cs_part -> scal[0]=colmax, scal[1]=rowmax ----------------
__global__ __launch_bounds__(256) void k_scal(const float* __restrict__ rs_part,
                                              const float* __restrict__ cs_part,
                                              float* __restrict__ scal) {
  __shared__ float red0[256];
  __shared__ float red1[256];
  int t = threadIdx.x;
  float mr = -1e30f, mc = -1e30f;
  for (int i = t; i < BH * Mm; i += 256) {
    mr = fmaxf(mr, rs_part[i]);
    mc = fmaxf(mc, cs_part[i]);
  }
  red0[t] = mr; red1[t] = mc;
  __syncthreads();
  for (int s = 128; s >= 1; s >>= 1) {
    if (t < s) { red0[t] = fmaxf(red0[t], red0[t + s]); red1[t] = fmaxf(red1[t], red1[t + s]); }
    __syncthreads();
  }
  if (t == 0) { scal[0] = red1[0]; scal[1] = red0[0]; }
}

// ---------------- z0 = X^T / (cmax*rmax) ----------------
__global__ __launch_bounds__(256) void k_zinit(const float* __restrict__ X, float* __restrict__ Z,
                                               const float* __restrict__ scal) {
  __shared__ float S[64][65];
  int bh = blockIdx.z;
  int bi = blockIdx.x * 64;  // out row block (i)
  int bj = blockIdx.y * 64;  // out col block (j) = in row block
  const float* Xp = X + (size_t)bh * Mm * Mm;
  float* Zp = Z + (size_t)bh * Mm * Mm;
  int c = threadIdx.x & 63, r0 = threadIdx.x >> 6;
  #pragma unroll
  for (int u = 0; u < 16; ++u) {
    int r = r0 + u * 4;
    S[r][c] = Xp[(size_t)(bj + r) * Mm + bi + c];
  }
  __syncthreads();
  float inv = 1.0f / (scal[0] * scal[1]);
  #pragma unroll
  for (int u = 0; u < 16; ++u) {
    int r = r0 + u * 4;
    Zp[(size_t)(bi + r) * Mm + bj + c] = S[c][r] * inv;
  }
}

// ---------------- batched NN mm: C = cscale * A @ (alpha*I + beta*B), rows=256 ----------------
__global__ __launch_bounds__(256) void k_bmm(const float* __restrict__ A, const float* __restrict__ Bm,
                                             float* __restrict__ C, int Kd, int Nc,
                                             float alpha, float beta, float cscale) {
  __shared__ float As[16][68];
  __shared__ float Bs[16][68];
  int bh = blockIdx.z;
  const float* Ap = A + (size_t)bh * Mm * Kd;
  const float* Bp = Bm + (size_t)bh * Kd * Nc;
  float* Cp = C + (size_t)bh * Mm * Nc;
  int row0 = blockIdx.y * 64, col0 = blockIdx.x * 64;
  int tid = threadIdx.x, tx = tid & 15, ty = tid >> 4;
  float acc[4][4];
  #pragma unroll
  for (int i = 0; i < 4; ++i)
    #pragma unroll
    for (int j = 0; j < 4; ++j) acc[i][j] = 0.f;
  const int ac = tid & 15, ar0 = tid >> 4;
  const int bc = tid & 63, br0 = tid >> 6;
  for (int kt = 0; kt < Kd; kt += 16) {
    #pragma unroll
    for (int u = 0; u < 4; ++u) {
      int ar = ar0 + u * 16;
      As[ac][ar] = Ap[(size_t)(row0 + ar) * Kd + kt + ac];
      int br = br0 + u * 4;
      float bv = Bp[(size_t)(kt + br) * Nc + col0 + bc] * beta;
      if (kt + br == col0 + bc) bv += alpha;
      Bs[br][bc] = bv;
    }
    __syncthreads();
    #pragma unroll
    for (int kq = 0; kq < 16; ++kq) {
      float4 a4 = *(const float4*)&As[kq][ty * 4];
      float4 b4 = *(const float4*)&Bs[kq][tx * 4];
      float av[4] = {a4.x, a4.y, a4.z, a4.w};
      float bv[4] = {b4.x, b4.y, b4.z, b4.w};
      #pragma unroll
      for (int i = 0; i < 4; ++i)
        #pragma unroll
        for (int j = 0; j < 4; ++j) acc[i][j] += av[i] * bv[j];
    }
    __syncthreads();
  }
  #pragma unroll
  for (int i = 0; i < 4; ++i)
    #pragma unroll
    for (int j = 0; j < 4; ++j)
      Cp[(size_t)(row0 + ty * 4 + i) * Nc + col0 + tx * 4 + j] = acc[i][j] * cscale;
}

// ---- fused: out_row = softmax(q@kl^T)@z2 ; val = out_row + conv33(v); 16-row max -> pool_part ----
// one wave handles 16 contiguous rows of one bh; writes its chunk max (no atomics)
__global__ __launch_bounds__(256) void k_attn1conv(const float* __restrict__ q, const float* __restrict__ kl,
                                                   const float* __restrict__ z2, const float* __restrict__ v,
                                                   const float* __restrict__ wres, float* __restrict__ pool_part) {
  int w = (blockIdx.x * 256 + threadIdx.x) >> 6;  // [0, BH*256)
  int lane = threadIdx.x & 63;
  int bh = w >> 8;
  int chunk = w & 255;
  int i0 = chunk << 4;
  int hh = bh & 7;
  const float* klb = kl + (size_t)bh * Mm * Dd;
  const float* zb  = z2 + (size_t)bh * Mm * Dd;
  const float* vb  = v + (size_t)bh * Nn * Dd + lane;
  const float* qb  = q + (size_t)bh * Nn * Dd;
  float wt[33];
  #pragma unroll
  for (int t = 0; t < 33; ++t) wt[t] = wres[hh * 33 + t];
  float wmax = -1e30f;
  for (int r = 0; r < 16; ++r) {
    const float* qr = qb + (size_t)(i0 + r) * Dd;
    float4 qrow[16];
    #pragma unroll
    for (int t = 0; t < 16; ++t) qrow[t] = ((const float4*)qr)[t];
    float m = -1e30f, s = 0.f, acc = 0.f;
    #pragma unroll
    for (int t = 0; t < 4; ++t) {
      const float* krow = klb + (size_t)(t * 64 + lane) * Dd;
      float logit = 0.f;
      #pragma unroll
      for (int u = 0; u < 16; ++u) {
        float4 k4 = ((const float4*)krow)[u];
        logit += qrow[u].x * k4.x + qrow[u].y * k4.y + qrow[u].z * k4.z + qrow[u].w * k4.w;
      }
      float tmax = wave_max(logit);
      float nm = fmaxf(m, tmax);
      float corr = __expf(m - nm);
      float p = __expf(logit - nm);
      s = s * corr + wave_sum(p);
      acc *= corr;
      m = nm;
      const float* zrow = zb + (size_t)(t * 64) * Dd + lane;
      #pragma unroll 16
      for (int j = 0; j < 64; ++j) {
        float pj = __shfl(p, j, 64);
        acc += pj * zrow[(size_t)j * Dd];
      }
    }
    // depthwise conv over sequence (window [i-16, i+16], zero pad)
    float conv = 0.f;
    int i = i0 + r;
    #pragma unroll
    for (int t = 0; t < 33; ++t) {
      int gi = i - 16 + t;
      float vv = (gi >= 0 && gi < Nn) ? vb[(size_t)gi * Dd] : 0.f;
      conv += wt[t] * vv;
    }
    wmax = fmaxf(wmax, acc / s + conv);
  }
  pool_part[((size_t)bh * Mm + chunk) * Dd + lane] = wmax;
}

// ---------------- reduce pool_part over 256 chunks -> pooled[bh][dd] ----------------
__global__ __launch_bounds__(64) void k_redmax(const float* __restrict__ pool_part, float* __restrict__ pooled) {
  int bh = blockIdx.x, dd = threadIdx.x;
  const float* p = pool_part + (size_t)bh * Mm * Dd + dd;
  float m = -1e30f;
  for (int c = 0; c < Mm; ++c) m = fmaxf(m, p[(size_t)c * Dd]);
  pooled[bh * Dd + dd] = m;
}

// ---------------- final: out = pooled @ w_out + b_out ----------------
__global__ __launch_bounds__(512) void k_final(const float* __restrict__ pooled, const float* __restrict__ wout,
                                               const float* __restrict__ bout, float* __restrict__ out) {
  int bh = blockIdx.x;
  int c = threadIdx.x;
  float accv = bout[c];
  #pragma unroll
  for (int dd = 0; dd < 64; ++dd) {
    accv += pooled[bh * 64 + dd] * wout[dd * DIMv + c];
  }
  out[(size_t)bh * DIMv + c] = accv;
}

extern "C" void kernel_launch(void* const* d_in, const int* in_sizes, int n_in,
                              void* d_out, int out_size, void* d_ws, size_t ws_size,
                              hipStream_t stream) {
  const float* x     = (const float*)d_in[0];
  const float* w_qkv = (const float*)d_in[1];
  const float* w_out = (const float*)d_in[2];
  const float* b_out = (const float*)d_in[3];
  const float* w_res = (const float*)d_in[4];
  float* out = (float*)d_out;
  float* ws = (float*)d_ws;

  // workspace layout (floats) — every buffer fully written before read; no atomics, no init:
  //   q    : NQD
  //   kbuf : NQD   (k; after k_attn3v reused as X,B1,B2,B3 = 4*MMsz)
  //   v    : NQD
  //   B4   : MMsz
  //   ql,kl,z3,z2 : 4*MDsz
  //   pool_part : MDsz
  //   rs_part, cs_part : BH*Mm each
  //   pooled : BH*Dd ; scal : 2
  const size_t need = ((size_t)3 * NQD + MMsz + 5 * MDsz + 2 * (BH * Mm) + BH * Dd + 2) * 4;
  if (ws_size < need) return;  // insufficient workspace -> fail validation cleanly, no OOB

  float* q    = ws;
  float* kbuf = q + NQD;
  float* v    = kbuf + NQD;
  float* B4   = v + NQD;
  float* ql   = B4 + MMsz;
  float* kl   = ql + MDsz;
  float* z3   = kl + MDsz;
  float* z2   = z3 + MDsz;
  float* pool_part = z2 + MDsz;
  float* rs_part   = pool_part + MDsz;
  float* cs_part   = rs_part + BH * Mm;
  float* pooled    = cs_part + BH * Mm;
  float* scal      = pooled + BH * Dd;

  float* X  = kbuf;
  float* B1 = kbuf + MMsz;
  float* B2 = kbuf + 2 * MMsz;
  float* B3 = kbuf + 3 * MMsz;

  k_qkv<<<dim3(512, 24), 256, 0, stream>>>(x, w_qkv, q, kbuf, v);
  k_lmeans<<<4096, 256, 0, stream>>>(q, kbuf, ql, kl);
  k_attn3v<<<(BH * Mm) / 4, 256, 0, stream>>>(ql, kbuf, v, z3);   // k dead after this
  k_sim2<<<dim3(4, 4, 64), 256, 0, stream>>>(ql, kl, X);          // X overwrites k
  k_softmax2<<<BH * Mm, 64, 0, stream>>>(X, rs_part);
  k_colsum<<<64, 256, 0, stream>>>(X, cs_part);
  k_scal<<<1, 256, 0, stream>>>(rs_part, cs_part, scal);
  k_zinit<<<dim3(4, 4, 64), 256, 0, stream>>>(X, B1, scal);

  // pinv: Z rotates through {B1,B2,B3,B4}; temps use the 3 free buffers
  float* Zc = B1;
  float* fr0 = B2; float* fr1 = B3; float* fr2 = B4;
  for (int it = 0; it < 6; ++it) {
    float* Ta = fr0; float* Tb = fr1; float* Tc = fr2;
    k_bmm<<<dim3(4, 4, 64), 256, 0, stream>>>(X,  Zc, Ta, 256, 256,  0.f,  1.f, 1.f);   // m1 = X@Z
    k_bmm<<<dim3(4, 4, 64), 256, 0, stream>>>(Ta, Ta, Tb, 256, 256,  7.f, -1.f, 1.f);   // m2 = m1@(7I-m1)
    k_bmm<<<dim3(4, 4, 64), 256, 0, stream>>>(Ta, Tb, Tc, 256, 256, 15.f, -1.f, 1.f);   // m3 = m1@(15I-m2)
    k_bmm<<<dim3(4, 4, 64), 256, 0, stream>>>(Zc, Tc, Ta, 256, 256, 13.f, -1.f, 0.25f); // z' = 0.25*Z@(13I-m3)
    float* newZ = Ta;
    fr0 = Zc;            // old Z becomes free; Tb(fr1), Tc(fr2) stay free
    Zc = newZ;
  }

  k_bmm<<<dim3(1, 4, 64), 256, 0, stream>>>(Zc, z3, z2, 256, 64, 0.f, 1.f, 1.f);        // z2 = pinv@z3

  k_attn1conv<<<(BH * 256) / 4, 256, 0, stream>>>(q, kl, z2, v, w_res, pool_part);
  k_redmax<<<BH, 64, 0, stream>>>(pool_part, pooled);
  k_final<<<BH, 512, 0, stream>>>(pooled, w_out, b_out, out);
}